// Round 1
// baseline (467.614 us; speedup 1.0000x reference)
//
#include <hip/hip_runtime.h>
#include <math.h>

#define BSZ 8
#define LQ  1024
#define LV  13294
#define NH  8
#define HD  32

// ---------------------------------------------------------------------------
// SGEMM: C = A @ W + bias
// A: [M,K] row-major, W: [K,N] row-major, bias: [N]
// mode 0: C[row*N + col]
// mode 1: v-scatter: row = b*LV + pix, col = h*32 + c
//         -> C[((b*NH + h)*LV + pix)*HD + c]   (layout [b][h][pix][c])
// Requires K % 16 == 0, N % 64 == 0. M may be ragged (guarded).
// ---------------------------------------------------------------------------
__global__ __launch_bounds__(256) void sgemm_kernel(
    const float* __restrict__ A, const float* __restrict__ W,
    const float* __restrict__ bias, float* __restrict__ C,
    int M, int N, int K, int mode)
{
    __shared__ float As[16][68];   // [k][m], padded: 68*4B = 272B rows (16B-aligned)
    __shared__ float Ws[16][68];   // [k][n]

    const int tid = threadIdx.x;
    const int tx = tid & 15, ty = tid >> 4;
    const int m0 = blockIdx.y * 64;
    const int n0 = blockIdx.x * 64;

    // A-tile load indices: 64 rows x 16 cols, one float4 per thread
    const int ra = tid >> 2;            // 0..63
    const int ka = (tid & 3) << 2;      // 0,4,8,12
    // W-tile load indices: 16 rows x 64 cols, one float4 per thread
    const int rw = tid >> 4;            // 0..15
    const int cw = (tid & 15) << 2;     // 0..60

    float acc[4][4];
#pragma unroll
    for (int i = 0; i < 4; ++i)
#pragma unroll
        for (int j = 0; j < 4; ++j) acc[i][j] = 0.f;

    for (int k0 = 0; k0 < K; k0 += 16) {
        float4 av = make_float4(0.f, 0.f, 0.f, 0.f);
        const int arow = m0 + ra;
        if (arow < M)
            av = *(const float4*)(A + (size_t)arow * K + (k0 + ka));
        As[ka + 0][ra] = av.x;
        As[ka + 1][ra] = av.y;
        As[ka + 2][ra] = av.z;
        As[ka + 3][ra] = av.w;

        *(float4*)&Ws[rw][cw] =
            *(const float4*)(W + (size_t)(k0 + rw) * N + (n0 + cw));

        __syncthreads();

#pragma unroll
        for (int k = 0; k < 16; ++k) {
            const float4 a4 = *(const float4*)&As[k][ty << 2];
            const float4 b4 = *(const float4*)&Ws[k][tx << 2];
            const float aa[4] = {a4.x, a4.y, a4.z, a4.w};
            const float bb[4] = {b4.x, b4.y, b4.z, b4.w};
#pragma unroll
            for (int i = 0; i < 4; ++i)
#pragma unroll
                for (int j = 0; j < 4; ++j)
                    acc[i][j] = fmaf(aa[i], bb[j], acc[i][j]);
        }
        __syncthreads();
    }

#pragma unroll
    for (int i = 0; i < 4; ++i) {
        const int row = m0 + (ty << 2) + i;
        if (row >= M) continue;
#pragma unroll
        for (int j = 0; j < 4; ++j) {
            const int col = n0 + (tx << 2) + j;
            const float val = acc[i][j] + bias[col];
            if (mode == 0) {
                C[(size_t)row * N + col] = val;
            } else {
                const int b   = row / LV;
                const int pix = row - b * LV;
                const int h   = col >> 5;
                const int c   = col & 31;
                C[(((size_t)(b * NH + h)) * LV + pix) * HD + c] = val;
            }
        }
    }
}

// ---------------------------------------------------------------------------
// Softmax over groups of 16 (one row per thread). rows = BSZ*LQ*NH.
// Input layout [B*Q][128] == [B*Q*8][16] contiguous.
// ---------------------------------------------------------------------------
__global__ __launch_bounds__(256) void softmax16_kernel(
    const float* __restrict__ in, float* __restrict__ out, int rows)
{
    const int r = blockIdx.x * blockDim.x + threadIdx.x;
    if (r >= rows) return;
    const float* p = in + (size_t)r * 16;
    float m = p[0];
#pragma unroll
    for (int i = 1; i < 16; ++i) m = fmaxf(m, p[i]);
    float e[16];
    float s = 0.f;
#pragma unroll
    for (int i = 0; i < 16; ++i) { e[i] = expf(p[i] - m); s += e[i]; }
    const float inv = 1.f / s;
    float* o = out + (size_t)r * 16;
#pragma unroll
    for (int i = 0; i < 16; ++i) o[i] = e[i] * inv;
}

// ---------------------------------------------------------------------------
// Deformable sampling.
// v:       [B][H][LV][HD]  (f32)
// so_raw:  [B*Q][256]  col = h*32 + l*8 + p*2 + {0:x,1:y}
// aw:      [B*Q][128]  softmaxed, col = h*16 + l*4 + p
// refp:    [B][Q][4][2]
// out_head:[B*Q][256]  col = h*32 + c
// Block: 256 threads = 32 queries x (8 lanes x float4 channels).
// Grid:  B*H*(LQ/32) blocks, grouped by (b,h) for L2 locality.
// ---------------------------------------------------------------------------
__device__ __forceinline__ void lvl_params(int l, int& Wl, int& Hl, int& st,
                                           float& invW, float& invH)
{
    if      (l == 0) { Wl = 100; Hl = 100; st = 0;     invW = 1.f/100.f; invH = 1.f/100.f; }
    else if (l == 1) { Wl = 50;  Hl = 50;  st = 10000; invW = 1.f/50.f;  invH = 1.f/50.f;  }
    else if (l == 2) { Wl = 25;  Hl = 25;  st = 12500; invW = 1.f/25.f;  invH = 1.f/25.f;  }
    else             { Wl = 13;  Hl = 13;  st = 13125; invW = 1.f/13.f;  invH = 1.f/13.f;  }
}

__global__ __launch_bounds__(256) void sample_kernel(
    const float* __restrict__ v,
    const float* __restrict__ so_raw,
    const float* __restrict__ aw,
    const float* __restrict__ refp,
    float* __restrict__ out_head)
{
    const int nchunk = LQ / 32;                 // 32
    const int blk    = blockIdx.x;
    const int chunk  = blk % nchunk;
    const int bh     = blk / nchunk;            // b*NH + h
    const int h      = bh & 7;
    const int b      = bh >> 3;

    const int sub = threadIdx.x >> 3;           // query in chunk: 0..31
    const int ln  = threadIdx.x & 7;            // channel group
    const int c0  = ln << 2;                    // 4 channels per lane

    const int q  = chunk * 32 + sub;
    const int rq = b * LQ + q;

    const float* vb = v + (size_t)bh * (LV * HD);

    float ax = 0.f, ay = 0.f, az = 0.f, aw4 = 0.f;

#pragma unroll
    for (int l = 0; l < 4; ++l) {
        int Wl, Hl, st; float invW, invH;
        lvl_params(l, Wl, Hl, st, invW, invH);
        const float fw = (float)Wl, fh = (float)Hl;

        const float rx = refp[((size_t)rq * 4 + l) * 2 + 0];
        const float ry = refp[((size_t)rq * 4 + l) * 2 + 1];

        const float* base = vb + (size_t)st * HD + c0;

#pragma unroll
        for (int p = 0; p < 4; ++p) {
            const int soi = rq * 256 + h * 32 + l * 8 + p * 2;
            const float sx = so_raw[soi];
            const float sy = so_raw[soi + 1];
            const float w  = aw[rq * 128 + h * 16 + l * 4 + p];

            const float x = (rx + sx * invW) * fw - 0.5f;
            const float y = (ry + sy * invH) * fh - 0.5f;

            const float xf = floorf(x), yf = floorf(y);
            const int x0 = (int)xf, y0 = (int)yf;
            const float wx1 = x - xf, wx0 = 1.f - wx1;
            const float wy1 = y - yf, wy0 = 1.f - wy1;

            const bool xv0 = (x0 >= 0) && (x0 < Wl);
            const bool xv1 = (x0 + 1 >= 0) && (x0 + 1 < Wl);
            const bool yv0 = (y0 >= 0) && (y0 < Hl);
            const bool yv1 = (y0 + 1 >= 0) && (y0 + 1 < Hl);

            float sx0 = 0.f, sy_ = 0.f, sz = 0.f, sw = 0.f;

            if (yv0) {
                const float* rowp = base + (size_t)y0 * Wl * HD;
                if (xv0) {
                    const float4 t = *(const float4*)(rowp + (size_t)x0 * HD);
                    const float wgt = wy0 * wx0;
                    sx0 += wgt * t.x; sy_ += wgt * t.y; sz += wgt * t.z; sw += wgt * t.w;
                }
                if (xv1) {
                    const float4 t = *(const float4*)(rowp + (size_t)(x0 + 1) * HD);
                    const float wgt = wy0 * wx1;
                    sx0 += wgt * t.x; sy_ += wgt * t.y; sz += wgt * t.z; sw += wgt * t.w;
                }
            }
            if (yv1) {
                const float* rowp = base + (size_t)(y0 + 1) * Wl * HD;
                if (xv0) {
                    const float4 t = *(const float4*)(rowp + (size_t)x0 * HD);
                    const float wgt = wy1 * wx0;
                    sx0 += wgt * t.x; sy_ += wgt * t.y; sz += wgt * t.z; sw += wgt * t.w;
                }
                if (xv1) {
                    const float4 t = *(const float4*)(rowp + (size_t)(x0 + 1) * HD);
                    const float wgt = wy1 * wx1;
                    sx0 += wgt * t.x; sy_ += wgt * t.y; sz += wgt * t.z; sw += wgt * t.w;
                }
            }
            ax = fmaf(w, sx0, ax);
            ay = fmaf(w, sy_, ay);
            az = fmaf(w, sz,  az);
            aw4 = fmaf(w, sw, aw4);
        }
    }

    float4 o; o.x = ax; o.y = ay; o.z = az; o.w = aw4;
    *(float4*)(out_head + (size_t)rq * 256 + (h << 5) + c0) = o;
}

// ---------------------------------------------------------------------------
extern "C" void kernel_launch(void* const* d_in, const int* in_sizes, int n_in,
                              void* d_out, int out_size, void* d_ws, size_t ws_size,
                              hipStream_t stream)
{
    const float* query = (const float*)d_in[0];
    const float* refp  = (const float*)d_in[1];
    const float* value = (const float*)d_in[2];
    // d_in[3] = value_spatial_shapes (compile-time constants, ignored)
    const float* so_w  = (const float*)d_in[4];
    const float* so_b  = (const float*)d_in[5];
    const float* aw_w  = (const float*)d_in[6];
    const float* aw_b  = (const float*)d_in[7];
    const float* vp_w  = (const float*)d_in[8];
    const float* vp_b  = (const float*)d_in[9];
    const float* op_w  = (const float*)d_in[10];
    const float* op_b  = (const float*)d_in[11];
    float* out = (float*)d_out;

    float* ws = (float*)d_ws;
    size_t off = 0;
    float* v        = ws + off; off += (size_t)BSZ * NH * LV * HD;  // 27,226,112
    float* so_raw   = ws + off; off += (size_t)BSZ * LQ * 256;      //  2,097,152
    float* aw_raw   = ws + off; off += (size_t)BSZ * LQ * 128;      //  1,048,576
    float* aw_n     = ws + off; off += (size_t)BSZ * LQ * 128;      //  1,048,576
    float* out_head = ws + off; off += (size_t)BSZ * LQ * 256;      //  2,097,152

    // 1) value projection -> v  [b][h][pix][c]
    {
        const int M = BSZ * LV, N = 256, K = 256;
        dim3 grid(N / 64, (M + 63) / 64);
        sgemm_kernel<<<grid, 256, 0, stream>>>(value, vp_w, vp_b, v, M, N, K, 1);
    }
    // 2) sampling-offset projection -> so_raw
    {
        const int M = BSZ * LQ, N = 256, K = 256;
        dim3 grid(N / 64, M / 64);
        sgemm_kernel<<<grid, 256, 0, stream>>>(query, so_w, so_b, so_raw, M, N, K, 0);
    }
    // 3) attention-weight projection -> aw_raw
    {
        const int M = BSZ * LQ, N = 128, K = 256;
        dim3 grid(N / 64, M / 64);
        sgemm_kernel<<<grid, 256, 0, stream>>>(query, aw_w, aw_b, aw_raw, M, N, K, 0);
    }
    // 4) softmax over 16 -> aw_n
    {
        const int rows = BSZ * LQ * NH;
        softmax16_kernel<<<rows / 256, 256, 0, stream>>>(aw_raw, aw_n, rows);
    }
    // 5) deformable sampling -> out_head
    {
        dim3 grid(BSZ * NH * (LQ / 32));
        sample_kernel<<<grid, 256, 0, stream>>>(v, so_raw, aw_n, refp, out_head);
    }
    // 6) output projection -> d_out
    {
        const int M = BSZ * LQ, N = 256, K = 256;
        dim3 grid(N / 64, M / 64);
        sgemm_kernel<<<grid, 256, 0, stream>>>(out_head, op_w, op_b, out, M, N, K, 0);
    }
}

// Round 2
// 310.870 us; speedup vs baseline: 1.5042x; 1.5042x over previous
//
#include <hip/hip_runtime.h>
#include <math.h>

#define BSZ 8
#define LQ  1024
#define LV  13294
#define NH  8
#define HD  32
#define VM  (BSZ * LV)   // 106352 rows of value

typedef __attribute__((ext_vector_type(8))) short bf16x8;
typedef __attribute__((ext_vector_type(4))) float f32x4;

__device__ static inline unsigned short f2bf(float f) {
    unsigned int u = __float_as_uint(f);
    unsigned int r = (u + 0x7FFFu + ((u >> 16) & 1u)) >> 16;
    return (unsigned short)r;
}
__device__ static inline float bf2f(unsigned short s) {
    return __uint_as_float(((unsigned int)s) << 16);
}
__device__ static inline void async_load16(const void* g, void* l) {
    __builtin_amdgcn_global_load_lds(
        (const __attribute__((address_space(1))) unsigned int*)g,
        (__attribute__((address_space(3))) unsigned int*)l, 16, 0, 0);
}

// ---------------------------------------------------------------------------
// Transpose+convert vp_w [k][n] f32 -> wT [n][k] bf16. 256x256.
// ---------------------------------------------------------------------------
__global__ __launch_bounds__(256) void wconv_kernel(
    const float* __restrict__ w, unsigned short* __restrict__ wT)
{
    const int n = blockIdx.x;      // 256 blocks
    const int k = threadIdx.x;     // 256 threads
    wT[n * 256 + k] = f2bf(w[k * 256 + n]);
}

// ---------------------------------------------------------------------------
// MFMA vproj: v = value @ vp_w + vp_b, scattered to [b][h][pix][c] bf16.
// BM=64, BN=256 (full N), BK=32. 256 threads = 4 waves, each 64m x 64n.
// A staged f32->bf16 in-register; W^T staged via global_load_lds (16B).
// ---------------------------------------------------------------------------
__global__ __launch_bounds__(256) void vproj_mfma_kernel(
    const float* __restrict__ A,          // [VM][256] f32
    const unsigned short* __restrict__ wT, // [256][256] bf16, [n][k]
    const float* __restrict__ bias,        // [256]
    unsigned short* __restrict__ v)        // [B][H][LV][32] bf16
{
    __shared__ __align__(16) unsigned short Asb[64 * 32];   // [m][k] 4 KB
    __shared__ __align__(16) unsigned short Wsb[256 * 32];  // [n][k] 16 KB

    const int tid  = threadIdx.x;
    const int w    = tid >> 6;        // wave 0..3
    const int lane = tid & 63;
    const int mrow = lane & 15;
    const int quad = lane >> 4;
    const int m0   = blockIdx.x * 64;

    f32x4 acc[4][4];
#pragma unroll
    for (int i = 0; i < 4; ++i)
#pragma unroll
        for (int j = 0; j < 4; ++j) acc[i][j] = (f32x4)0.f;

    // A-staging indices: 64 rows x 8 float4; thread covers 2 rows' chunks
    const int am = tid >> 3;          // 0..31
    const int ak = (tid & 7) << 2;    // 0,4,...,28

    for (int k0 = 0; k0 < 256; k0 += 32) {
        __syncthreads();
        // stage A (f32 -> bf16)
#pragma unroll
        for (int i = 0; i < 2; ++i) {
            const int m  = am + 32 * i;
            const int gm = m0 + m;
            float4 av = make_float4(0.f, 0.f, 0.f, 0.f);
            if (gm < VM)
                av = *(const float4*)(A + (size_t)gm * 256 + k0 + ak);
            ushort4 bv;
            bv.x = f2bf(av.x); bv.y = f2bf(av.y);
            bv.z = f2bf(av.z); bv.w = f2bf(av.w);
            *(ushort4*)&Asb[m * 32 + ak] = bv;
        }
        // stage W^T via async 16B direct-to-LDS: 16 instrs cover 256 rows
#pragma unroll
        for (int j = 0; j < 4; ++j) {
            const int base_n = w * 64 + j * 16;
            const int n      = base_n + (lane >> 2);
            const unsigned short* gp = wT + (size_t)n * 256 + k0 + (lane & 3) * 8;
            async_load16(gp, &Wsb[base_n * 32]);
        }
        __syncthreads();

        bf16x8 af[4], bfr[4];
#pragma unroll
        for (int i = 0; i < 4; ++i)
            af[i] = *(const bf16x8*)&Asb[(i * 16 + mrow) * 32 + quad * 8];
#pragma unroll
        for (int j = 0; j < 4; ++j)
            bfr[j] = *(const bf16x8*)&Wsb[(w * 64 + j * 16 + mrow) * 32 + quad * 8];
#pragma unroll
        for (int i = 0; i < 4; ++i)
#pragma unroll
            for (int j = 0; j < 4; ++j)
                acc[i][j] = __builtin_amdgcn_mfma_f32_16x16x32_bf16(
                    af[i], bfr[j], acc[i][j], 0, 0, 0);
    }

    // epilogue: scatter bf16 into [b][h][pix][c]
#pragma unroll
    for (int i = 0; i < 4; ++i) {
#pragma unroll
        for (int r = 0; r < 4; ++r) {
            const int gm = m0 + i * 16 + quad * 4 + r;
            if (gm >= VM) continue;
            const unsigned int b   = (unsigned int)gm / (unsigned int)LV;
            const unsigned int pix = (unsigned int)gm - b * (unsigned int)LV;
#pragma unroll
            for (int j = 0; j < 4; ++j) {
                const int gn = w * 64 + j * 16 + mrow;
                const float val = acc[i][j][r] + bias[gn];
                const int h = gn >> 5, c = gn & 31;
                v[(((size_t)(b * NH + h)) * LV + pix) * HD + c] = f2bf(val);
            }
        }
    }
}

// ---------------------------------------------------------------------------
// f32 SGEMM (vector ALU) for the small projections. C = A@W + bias, [M,N].
// ---------------------------------------------------------------------------
__global__ __launch_bounds__(256) void sgemm_kernel(
    const float* __restrict__ A, const float* __restrict__ W,
    const float* __restrict__ bias, float* __restrict__ C,
    int M, int N, int K)
{
    __shared__ float As[16][68];
    __shared__ float Ws[16][68];

    const int tid = threadIdx.x;
    const int tx = tid & 15, ty = tid >> 4;
    const int m0 = blockIdx.y * 64;
    const int n0 = blockIdx.x * 64;

    const int ra = tid >> 2;
    const int ka = (tid & 3) << 2;
    const int rw = tid >> 4;
    const int cw = (tid & 15) << 2;

    float acc[4][4];
#pragma unroll
    for (int i = 0; i < 4; ++i)
#pragma unroll
        for (int j = 0; j < 4; ++j) acc[i][j] = 0.f;

    for (int k0 = 0; k0 < K; k0 += 16) {
        float4 av = make_float4(0.f, 0.f, 0.f, 0.f);
        const int arow = m0 + ra;
        if (arow < M)
            av = *(const float4*)(A + (size_t)arow * K + (k0 + ka));
        As[ka + 0][ra] = av.x;
        As[ka + 1][ra] = av.y;
        As[ka + 2][ra] = av.z;
        As[ka + 3][ra] = av.w;
        *(float4*)&Ws[rw][cw] =
            *(const float4*)(W + (size_t)(k0 + rw) * N + (n0 + cw));
        __syncthreads();
#pragma unroll
        for (int k = 0; k < 16; ++k) {
            const float4 a4 = *(const float4*)&As[k][ty << 2];
            const float4 b4 = *(const float4*)&Ws[k][tx << 2];
            const float aa[4] = {a4.x, a4.y, a4.z, a4.w};
            const float bb[4] = {b4.x, b4.y, b4.z, b4.w};
#pragma unroll
            for (int i = 0; i < 4; ++i)
#pragma unroll
                for (int j = 0; j < 4; ++j)
                    acc[i][j] = fmaf(aa[i], bb[j], acc[i][j]);
        }
        __syncthreads();
    }

#pragma unroll
    for (int i = 0; i < 4; ++i) {
        const int row = m0 + (ty << 2) + i;
        if (row >= M) continue;
#pragma unroll
        for (int j = 0; j < 4; ++j) {
            const int col = n0 + (tx << 2) + j;
            C[(size_t)row * N + col] = acc[i][j] + bias[col];
        }
    }
}

// ---------------------------------------------------------------------------
// Softmax over groups of 16.
// ---------------------------------------------------------------------------
__global__ __launch_bounds__(256) void softmax16_kernel(
    const float* __restrict__ in, float* __restrict__ out, int rows)
{
    const int r = blockIdx.x * blockDim.x + threadIdx.x;
    if (r >= rows) return;
    const float* p = in + (size_t)r * 16;
    float m = p[0];
#pragma unroll
    for (int i = 1; i < 16; ++i) m = fmaxf(m, p[i]);
    float e[16];
    float s = 0.f;
#pragma unroll
    for (int i = 0; i < 16; ++i) { e[i] = expf(p[i] - m); s += e[i]; }
    const float inv = 1.f / s;
    float* o = out + (size_t)r * 16;
#pragma unroll
    for (int i = 0; i < 16; ++i) o[i] = e[i] * inv;
}

// ---------------------------------------------------------------------------
// Sampling v2: bf16 v, cooperative per-point precompute in LDS, branch-free
// gathers, XCD-aware swizzle.
// Block: 256 threads = 32 queries x 8 lanes. Grid: 2048.
// ---------------------------------------------------------------------------
__global__ __launch_bounds__(256) void sample_kernel(
    const unsigned short* __restrict__ v,   // [B][H][LV][32] bf16
    const float* __restrict__ so_raw,       // [B*Q][256]
    const float* __restrict__ aw,           // [B*Q][128] softmaxed
    const float* __restrict__ refp,         // [B][Q][4][2]
    float* __restrict__ out_head)           // [B*Q][256] f32
{
    __shared__ __align__(16) float wts[512][4];
    __shared__ __align__(16) int   offs[512][4];

    // swizzle: each XCD (blk&7) owns one batch, streams its 8 head slices
    const int blk   = blockIdx.x;
    const int xcd   = blk & 7;
    const int j     = blk >> 3;            // 0..255
    const int bh    = xcd * 8 + (j >> 5);  // b = xcd, h = j>>5
    const int chunk = j & 31;
    const int h     = bh & 7;
    const int b     = bh >> 3;

    const int t = threadIdx.x;

    // ---- phase 1: 512 point-tasks (32 q x 16 pts), 2 per thread ----
#pragma unroll
    for (int rep = 0; rep < 2; ++rep) {
        const int s  = t + rep * 256;
        const int qq = s >> 4;
        const int pt = s & 15;
        const int l  = pt >> 2;
        const int p  = pt & 3;
        const int rq = b * LQ + chunk * 32 + qq;

        const int Wl = (l == 0) ? 100 : (l == 1) ? 50 : (l == 2) ? 25 : 13;
        const int st = (l == 0) ? 0 : (l == 1) ? 10000 : (l == 2) ? 12500 : 13125;
        const float invW = (l == 0) ? 0.01f : (l == 1) ? 0.02f : (l == 2) ? 0.04f
                                            : (1.0f / 13.0f);
        const float fw = (float)Wl;

        const float rx = refp[((size_t)rq * 4 + l) * 2 + 0];
        const float ry = refp[((size_t)rq * 4 + l) * 2 + 1];
        const int soi  = rq * 256 + h * 32 + l * 8 + p * 2;
        const float sx = so_raw[soi];
        const float sy = so_raw[soi + 1];
        const float wgt = aw[rq * 128 + h * 16 + l * 4 + p];

        const float x = (rx + sx * invW) * fw - 0.5f;
        const float y = (ry + sy * invW) * fw - 0.5f;   // square levels: invH==invW

        const float xf = floorf(x), yf = floorf(y);
        const int x0 = (int)xf, y0 = (int)yf;
        const float wx1 = x - xf, wx0 = 1.f - wx1;
        const float wy1 = y - yf, wy0 = 1.f - wy1;

        const float vx0 = (x0 >= 0 && x0 < Wl) ? 1.f : 0.f;
        const float vx1 = (x0 + 1 >= 0 && x0 + 1 < Wl) ? 1.f : 0.f;
        const float vy0 = (y0 >= 0 && y0 < Wl) ? 1.f : 0.f;
        const float vy1 = (y0 + 1 >= 0 && y0 + 1 < Wl) ? 1.f : 0.f;

        const int xc0 = min(max(x0, 0), Wl - 1);
        const int xc1 = min(max(x0 + 1, 0), Wl - 1);
        const int yc0 = min(max(y0, 0), Wl - 1);
        const int yc1 = min(max(y0 + 1, 0), Wl - 1);

        const int row0 = st + yc0 * Wl;
        const int row1 = st + yc1 * Wl;

        wts[s][0] = wgt * wy0 * wx0 * vy0 * vx0;
        wts[s][1] = wgt * wy0 * wx1 * vy0 * vx1;
        wts[s][2] = wgt * wy1 * wx0 * vy1 * vx0;
        wts[s][3] = wgt * wy1 * wx1 * vy1 * vx1;
        offs[s][0] = (row0 + xc0) * HD;
        offs[s][1] = (row0 + xc1) * HD;
        offs[s][2] = (row1 + xc0) * HD;
        offs[s][3] = (row1 + xc1) * HD;
    }
    __syncthreads();

    // ---- phase 2: gather + accumulate ----
    const int qq = t >> 3;
    const int ln = t & 7;
    const unsigned short* vb = v + (size_t)bh * (LV * HD) + ln * 4;

    float a0 = 0.f, a1 = 0.f, a2 = 0.f, a3 = 0.f;

#pragma unroll 4
    for (int pt = 0; pt < 16; ++pt) {
        const int s = qq * 16 + pt;
        const float4 w4 = *(const float4*)&wts[s][0];
        const int4   o4 = *(const int4*)&offs[s][0];

        const ushort4 u0 = *(const ushort4*)(vb + o4.x);
        const ushort4 u1 = *(const ushort4*)(vb + o4.y);
        const ushort4 u2 = *(const ushort4*)(vb + o4.z);
        const ushort4 u3 = *(const ushort4*)(vb + o4.w);

        a0 = fmaf(w4.x, bf2f(u0.x), a0);
        a1 = fmaf(w4.x, bf2f(u0.y), a1);
        a2 = fmaf(w4.x, bf2f(u0.z), a2);
        a3 = fmaf(w4.x, bf2f(u0.w), a3);
        a0 = fmaf(w4.y, bf2f(u1.x), a0);
        a1 = fmaf(w4.y, bf2f(u1.y), a1);
        a2 = fmaf(w4.y, bf2f(u1.z), a2);
        a3 = fmaf(w4.y, bf2f(u1.w), a3);
        a0 = fmaf(w4.z, bf2f(u2.x), a0);
        a1 = fmaf(w4.z, bf2f(u2.y), a1);
        a2 = fmaf(w4.z, bf2f(u2.z), a2);
        a3 = fmaf(w4.z, bf2f(u2.w), a3);
        a0 = fmaf(w4.w, bf2f(u3.x), a0);
        a1 = fmaf(w4.w, bf2f(u3.y), a1);
        a2 = fmaf(w4.w, bf2f(u3.z), a2);
        a3 = fmaf(w4.w, bf2f(u3.w), a3);
    }

    const int rq = b * LQ + chunk * 32 + qq;
    float4 o; o.x = a0; o.y = a1; o.z = a2; o.w = a3;
    *(float4*)(out_head + (size_t)rq * 256 + (h << 5) + (ln << 2)) = o;
}

// ---------------------------------------------------------------------------
extern "C" void kernel_launch(void* const* d_in, const int* in_sizes, int n_in,
                              void* d_out, int out_size, void* d_ws, size_t ws_size,
                              hipStream_t stream)
{
    const float* query = (const float*)d_in[0];
    const float* refp  = (const float*)d_in[1];
    const float* value = (const float*)d_in[2];
    const float* so_w  = (const float*)d_in[4];
    const float* so_b  = (const float*)d_in[5];
    const float* aw_w  = (const float*)d_in[6];
    const float* aw_b  = (const float*)d_in[7];
    const float* vp_w  = (const float*)d_in[8];
    const float* vp_b  = (const float*)d_in[9];
    const float* op_w  = (const float*)d_in[10];
    const float* op_b  = (const float*)d_in[11];
    float* out = (float*)d_out;

    float* ws = (float*)d_ws;
    size_t off = 0;
    unsigned short* v = (unsigned short*)(ws + off);
    off += (size_t)BSZ * NH * LV * HD / 2;                          // bf16, 13,613,056 floats
    unsigned short* wT = (unsigned short*)(ws + off); off += 32768; // 256x256 bf16
    float* so_raw   = ws + off; off += (size_t)BSZ * LQ * 256;
    float* aw_raw   = ws + off; off += (size_t)BSZ * LQ * 128;
    float* aw_n     = ws + off; off += (size_t)BSZ * LQ * 128;
    float* out_head = ws + off; off += (size_t)BSZ * LQ * 256;

    // 0) transpose+convert vp_w
    wconv_kernel<<<256, 256, 0, stream>>>(vp_w, wT);

    // 1) value projection (MFMA bf16) -> v [b][h][pix][c]
    {
        dim3 grid((VM + 63) / 64);
        vproj_mfma_kernel<<<grid, 256, 0, stream>>>(value, wT, vp_b, v);
    }
    // 2) sampling-offset projection -> so_raw (f32)
    {
        dim3 grid(256 / 64, BSZ * LQ / 64);
        sgemm_kernel<<<grid, 256, 0, stream>>>(query, so_w, so_b, so_raw,
                                               BSZ * LQ, 256, 256);
    }
    // 3) attention-weight projection -> aw_raw (f32)
    {
        dim3 grid(128 / 64, BSZ * LQ / 64);
        sgemm_kernel<<<grid, 256, 0, stream>>>(query, aw_w, aw_b, aw_raw,
                                               BSZ * LQ, 128, 256);
    }
    // 4) softmax over 16 -> aw_n
    {
        const int rows = BSZ * LQ * NH;
        softmax16_kernel<<<rows / 256, 256, 0, stream>>>(aw_raw, aw_n, rows);
    }
    // 5) deformable sampling -> out_head
    {
        dim3 grid(BSZ * NH * (LQ / 32));
        sample_kernel<<<grid, 256, 0, stream>>>(v, so_raw, aw_n, refp, out_head);
    }
    // 6) output projection -> d_out (f32)
    {
        dim3 grid(256 / 64, BSZ * LQ / 64);
        sgemm_kernel<<<grid, 256, 0, stream>>>(out_head, op_w, op_b, out,
                                               BSZ * LQ, 256, 256);
    }
}

// Round 3
// 287.163 us; speedup vs baseline: 1.6284x; 1.0826x over previous
//
#include <hip/hip_runtime.h>
#include <math.h>

#define BSZ 8
#define LQ  1024
#define LV  13294
#define NH  8
#define HD  32
#define VM  (BSZ * LV)   // 106352 rows of value

typedef __attribute__((ext_vector_type(8))) short bf16x8;
typedef __attribute__((ext_vector_type(8))) unsigned short u16x8;
typedef __attribute__((ext_vector_type(4))) float f32x4;

__device__ static inline unsigned short f2bf(float f) {
    unsigned int u = __float_as_uint(f);
    unsigned int r = (u + 0x7FFFu + ((u >> 16) & 1u)) >> 16;
    return (unsigned short)r;
}
__device__ static inline float bf2f(unsigned short s) {
    return __uint_as_float(((unsigned int)s) << 16);
}

// ---------------------------------------------------------------------------
// Transpose+convert vp_w [k][n] f32 -> wT [n][k] bf16. 256x256.
// ---------------------------------------------------------------------------
__global__ __launch_bounds__(256) void wconv_kernel(
    const float* __restrict__ w, unsigned short* __restrict__ wT)
{
    const int n = blockIdx.x;
    const int k = threadIdx.x;
    wT[n * 256 + k] = f2bf(w[k * 256 + n]);
}

// ---------------------------------------------------------------------------
// vproj: v = value @ vp_w + vp_b -> [b][h][pix][c] bf16.
// One 64-row M-tile per block, full N=256, full K=256.
// W^T held in registers (32 frags/lane); A staged once to LDS (XOR-swizzled
// 16B chunks); ONE barrier per block; 128 MFMA per wave back-to-back.
// ---------------------------------------------------------------------------
__global__ __launch_bounds__(256, 2) void vproj_mfma_kernel(
    const float* __restrict__ A,            // [VM][256] f32
    const unsigned short* __restrict__ wT,  // [256][256] bf16 [n][k]
    const float* __restrict__ bias,         // [256]
    unsigned short* __restrict__ v)         // [B][H][LV][32] bf16
{
    __shared__ __align__(16) unsigned short Asb[64 * 256];  // 32 KB [m][k-swizzled]

    const int tid  = threadIdx.x;
    const int w    = tid >> 6;
    const int lane = tid & 63;
    const int mrow = lane & 15;
    const int quad = lane >> 4;
    const int m0   = blockIdx.x * 64;

    // ---- W fragments: wave w owns cols [w*64, w*64+64) ----
    bf16x8 wf[4][8];
#pragma unroll
    for (int j = 0; j < 4; ++j) {
        const int n = w * 64 + j * 16 + mrow;
#pragma unroll
        for (int kc = 0; kc < 8; ++kc)
            wf[j][kc] = *(const bf16x8*)(const void*)(wT + (size_t)n * 256 + kc * 32 + quad * 8);
    }
    float bj[4];
#pragma unroll
    for (int j = 0; j < 4; ++j) bj[j] = bias[w * 64 + j * 16 + mrow];

    // ---- stage A tile (f32 -> bf16), one pass, swizzled 16B chunks ----
    {
        const int m  = tid >> 2;          // 0..63
        const int kq = tid & 3;           // k-quadrant: 64 floats each
        const int gm = m0 + m;
        const float* ap = A + (size_t)gm * 256 + kq * 64;
        unsigned short* lrow = &Asb[m * 256];
#pragma unroll
        for (int u = 0; u < 8; ++u) {
            const int c  = kq * 8 + u;        // logical 16B chunk (8 bf16)
            const int cp = c ^ (m & 31);      // XOR swizzle breaks bank aliasing
            u16x8 b8 = (u16x8)0;
            if (gm < VM) {
                const float4 f0 = *(const float4*)(ap + u * 8);
                const float4 f1 = *(const float4*)(ap + u * 8 + 4);
                b8[0] = f2bf(f0.x); b8[1] = f2bf(f0.y);
                b8[2] = f2bf(f0.z); b8[3] = f2bf(f0.w);
                b8[4] = f2bf(f1.x); b8[5] = f2bf(f1.y);
                b8[6] = f2bf(f1.z); b8[7] = f2bf(f1.w);
            }
            *(u16x8*)(lrow + cp * 8) = b8;
        }
    }
    __syncthreads();

    // ---- compute: 8 k-chunks x 4 m x 4 n MFMA ----
    f32x4 acc[4][4];
#pragma unroll
    for (int i = 0; i < 4; ++i)
#pragma unroll
        for (int j = 0; j < 4; ++j) acc[i][j] = (f32x4)0.f;

#pragma unroll
    for (int kc = 0; kc < 8; ++kc) {
        bf16x8 af[4];
#pragma unroll
        for (int i = 0; i < 4; ++i) {
            const int mr = i * 16 + mrow;
            const int c  = kc * 4 + quad;
            const int cp = c ^ (mr & 31);
            af[i] = *(const bf16x8*)(const void*)&Asb[mr * 256 + cp * 8];
        }
#pragma unroll
        for (int i = 0; i < 4; ++i)
#pragma unroll
            for (int j = 0; j < 4; ++j)
                acc[i][j] = __builtin_amdgcn_mfma_f32_16x16x32_bf16(
                    af[i], wf[j][kc], acc[i][j], 0, 0, 0);
    }

    // ---- epilogue: bias + bf16 scatter into [b][h][pix][c] ----
#pragma unroll
    for (int i = 0; i < 4; ++i) {
#pragma unroll
        for (int r = 0; r < 4; ++r) {
            const int gm = m0 + i * 16 + quad * 4 + r;
            if (gm >= VM) continue;
            const unsigned int b   = (unsigned int)gm / (unsigned int)LV;
            const unsigned int pix = (unsigned int)gm - b * (unsigned int)LV;
#pragma unroll
            for (int j = 0; j < 4; ++j) {
                const int gn = w * 64 + j * 16 + mrow;
                const int h = gn >> 5, c = gn & 31;
                v[(((size_t)(b * NH + h)) * LV + pix) * HD + c] =
                    f2bf(acc[i][j][r] + bj[j]);
            }
        }
    }
}

// ---------------------------------------------------------------------------
// Fused so+aw projection (f32 vector sgemm). A = query [8192][256].
// Grid x: 6 column-tiles of 64 (0..3 -> so_w N=256, 4..5 -> aw_w N=128).
// ---------------------------------------------------------------------------
__global__ __launch_bounds__(256) void qproj_kernel(
    const float* __restrict__ A,
    const float* __restrict__ so_w, const float* __restrict__ so_b,
    const float* __restrict__ aw_w, const float* __restrict__ aw_b,
    float* __restrict__ so_raw, float* __restrict__ aw_raw)
{
    __shared__ float As[16][68];
    __shared__ float Ws[16][68];

    const int tid = threadIdx.x;
    const int tx = tid & 15, ty = tid >> 4;
    const int m0 = blockIdx.y * 64;
    const int n0g = blockIdx.x * 64;

    const float* W; const float* bias; float* C; int N, n0;
    if (n0g < 256) { W = so_w; bias = so_b; C = so_raw; N = 256; n0 = n0g; }
    else           { W = aw_w; bias = aw_b; C = aw_raw; N = 128; n0 = n0g - 256; }

    const int ra = tid >> 2;
    const int ka = (tid & 3) << 2;
    const int rw = tid >> 4;
    const int cw = (tid & 15) << 2;

    float acc[4][4];
#pragma unroll
    for (int i = 0; i < 4; ++i)
#pragma unroll
        for (int j = 0; j < 4; ++j) acc[i][j] = 0.f;

    for (int k0 = 0; k0 < 256; k0 += 16) {
        const float4 av = *(const float4*)(A + (size_t)(m0 + ra) * 256 + (k0 + ka));
        As[ka + 0][ra] = av.x;
        As[ka + 1][ra] = av.y;
        As[ka + 2][ra] = av.z;
        As[ka + 3][ra] = av.w;
        *(float4*)&Ws[rw][cw] =
            *(const float4*)(W + (size_t)(k0 + rw) * N + (n0 + cw));
        __syncthreads();
#pragma unroll
        for (int k = 0; k < 16; ++k) {
            const float4 a4 = *(const float4*)&As[k][ty << 2];
            const float4 b4 = *(const float4*)&Ws[k][tx << 2];
            const float aa[4] = {a4.x, a4.y, a4.z, a4.w};
            const float bb[4] = {b4.x, b4.y, b4.z, b4.w};
#pragma unroll
            for (int i = 0; i < 4; ++i)
#pragma unroll
                for (int j = 0; j < 4; ++j)
                    acc[i][j] = fmaf(aa[i], bb[j], acc[i][j]);
        }
        __syncthreads();
    }

#pragma unroll
    for (int i = 0; i < 4; ++i) {
        const int row = m0 + (ty << 2) + i;
#pragma unroll
        for (int j = 0; j < 4; ++j) {
            const int col = n0 + (tx << 2) + j;
            C[(size_t)row * N + col] = acc[i][j] + bias[col];
        }
    }
}

// ---------------------------------------------------------------------------
// Plain f32 sgemm for the output projection. C = A@W + bias. M=8192,N=K=256.
// ---------------------------------------------------------------------------
__global__ __launch_bounds__(256) void sgemm_kernel(
    const float* __restrict__ A, const float* __restrict__ W,
    const float* __restrict__ bias, float* __restrict__ C)
{
    __shared__ float As[16][68];
    __shared__ float Ws[16][68];

    const int tid = threadIdx.x;
    const int tx = tid & 15, ty = tid >> 4;
    const int m0 = blockIdx.y * 64;
    const int n0 = blockIdx.x * 64;

    const int ra = tid >> 2;
    const int ka = (tid & 3) << 2;
    const int rw = tid >> 4;
    const int cw = (tid & 15) << 2;

    float acc[4][4];
#pragma unroll
    for (int i = 0; i < 4; ++i)
#pragma unroll
        for (int j = 0; j < 4; ++j) acc[i][j] = 0.f;

    for (int k0 = 0; k0 < 256; k0 += 16) {
        const float4 av = *(const float4*)(A + (size_t)(m0 + ra) * 256 + (k0 + ka));
        As[ka + 0][ra] = av.x;
        As[ka + 1][ra] = av.y;
        As[ka + 2][ra] = av.z;
        As[ka + 3][ra] = av.w;
        *(float4*)&Ws[rw][cw] =
            *(const float4*)(W + (size_t)(k0 + rw) * 256 + (n0 + cw));
        __syncthreads();
#pragma unroll
        for (int k = 0; k < 16; ++k) {
            const float4 a4 = *(const float4*)&As[k][ty << 2];
            const float4 b4 = *(const float4*)&Ws[k][tx << 2];
            const float aa[4] = {a4.x, a4.y, a4.z, a4.w};
            const float bb[4] = {b4.x, b4.y, b4.z, b4.w};
#pragma unroll
            for (int i = 0; i < 4; ++i)
#pragma unroll
                for (int j = 0; j < 4; ++j)
                    acc[i][j] = fmaf(aa[i], bb[j], acc[i][j]);
        }
        __syncthreads();
    }

#pragma unroll
    for (int i = 0; i < 4; ++i) {
        const int row = m0 + (ty << 2) + i;
#pragma unroll
        for (int j = 0; j < 4; ++j) {
            const int col = n0 + (tx << 2) + j;
            C[(size_t)row * 256 + col] = acc[i][j] + bias[col];
        }
    }
}

// ---------------------------------------------------------------------------
// Sampling with inline softmax. bf16 v, per-point precompute in LDS,
// branch-free gathers, XCD-aware swizzle.
// Block: 256 threads = 32 queries x 8 lanes. Grid: 2048.
// ---------------------------------------------------------------------------
__global__ __launch_bounds__(256) void sample_kernel(
    const unsigned short* __restrict__ v,   // [B][H][LV][32] bf16
    const float* __restrict__ so_raw,       // [B*Q][256]
    const float* __restrict__ aw_raw,       // [B*Q][128] raw logits
    const float* __restrict__ refp,         // [B][Q][4][2]
    float* __restrict__ out_head)           // [B*Q][256] f32
{
    __shared__ __align__(16) float wts[512][4];
    __shared__ __align__(16) int   offs[512][4];

    const int blk   = blockIdx.x;
    const int xcd   = blk & 7;
    const int j     = blk >> 3;
    const int bh    = xcd * 8 + (j >> 5);
    const int chunk = j & 31;
    const int h     = bh & 7;
    const int b     = bh >> 3;

    const int t = threadIdx.x;

    // ---- phase 1: 512 point-tasks (32 q x 16 pts), inline softmax ----
#pragma unroll
    for (int rep = 0; rep < 2; ++rep) {
        const int s  = t + rep * 256;
        const int qq = s >> 4;
        const int pt = s & 15;
        const int l  = pt >> 2;
        const int p  = pt & 3;
        const int rq = b * LQ + chunk * 32 + qq;

        const int Wl = (l == 0) ? 100 : (l == 1) ? 50 : (l == 2) ? 25 : 13;
        const int st = (l == 0) ? 0 : (l == 1) ? 10000 : (l == 2) ? 12500 : 13125;
        const float invW = (l == 0) ? 0.01f : (l == 1) ? 0.02f : (l == 2) ? 0.04f
                                            : (1.0f / 13.0f);
        const float fw = (float)Wl;

        // inline softmax over the 16 points of this (rq,h) row
        const float logit = aw_raw[rq * 128 + h * 16 + pt];
        float mx = logit;
#pragma unroll
        for (int d = 1; d < 16; d <<= 1) mx = fmaxf(mx, __shfl_xor(mx, d, 16));
        const float e = expf(logit - mx);
        float sm = e;
#pragma unroll
        for (int d = 1; d < 16; d <<= 1) sm += __shfl_xor(sm, d, 16);
        const float wgt = e / sm;

        const float rx = refp[((size_t)rq * 4 + l) * 2 + 0];
        const float ry = refp[((size_t)rq * 4 + l) * 2 + 1];
        const int soi  = rq * 256 + h * 32 + l * 8 + p * 2;
        const float sx = so_raw[soi];
        const float sy = so_raw[soi + 1];

        const float x = (rx + sx * invW) * fw - 0.5f;
        const float y = (ry + sy * invW) * fw - 0.5f;   // square levels

        const float xf = floorf(x), yf = floorf(y);
        const int x0 = (int)xf, y0 = (int)yf;
        const float wx1 = x - xf, wx0 = 1.f - wx1;
        const float wy1 = y - yf, wy0 = 1.f - wy1;

        const float vx0 = (x0 >= 0 && x0 < Wl) ? 1.f : 0.f;
        const float vx1 = (x0 + 1 >= 0 && x0 + 1 < Wl) ? 1.f : 0.f;
        const float vy0 = (y0 >= 0 && y0 < Wl) ? 1.f : 0.f;
        const float vy1 = (y0 + 1 >= 0 && y0 + 1 < Wl) ? 1.f : 0.f;

        const int xc0 = min(max(x0, 0), Wl - 1);
        const int xc1 = min(max(x0 + 1, 0), Wl - 1);
        const int yc0 = min(max(y0, 0), Wl - 1);
        const int yc1 = min(max(y0 + 1, 0), Wl - 1);

        const int row0 = st + yc0 * Wl;
        const int row1 = st + yc1 * Wl;

        wts[s][0] = wgt * wy0 * wx0 * vy0 * vx0;
        wts[s][1] = wgt * wy0 * wx1 * vy0 * vx1;
        wts[s][2] = wgt * wy1 * wx0 * vy1 * vx0;
        wts[s][3] = wgt * wy1 * wx1 * vy1 * vx1;
        offs[s][0] = (row0 + xc0) * HD;
        offs[s][1] = (row0 + xc1) * HD;
        offs[s][2] = (row1 + xc0) * HD;
        offs[s][3] = (row1 + xc1) * HD;
    }
    __syncthreads();

    // ---- phase 2: gather + accumulate ----
    const int qq = t >> 3;
    const int ln = t & 7;
    const unsigned short* vb = v + (size_t)bh * (LV * HD) + ln * 4;

    float a0 = 0.f, a1 = 0.f, a2 = 0.f, a3 = 0.f;

#pragma unroll 4
    for (int pt = 0; pt < 16; ++pt) {
        const int s = qq * 16 + pt;
        const float4 w4 = *(const float4*)&wts[s][0];
        const int4   o4 = *(const int4*)&offs[s][0];

        const ushort4 u0 = *(const ushort4*)(vb + o4.x);
        const ushort4 u1 = *(const ushort4*)(vb + o4.y);
        const ushort4 u2 = *(const ushort4*)(vb + o4.z);
        const ushort4 u3 = *(const ushort4*)(vb + o4.w);

        a0 = fmaf(w4.x, bf2f(u0.x), a0);
        a1 = fmaf(w4.x, bf2f(u0.y), a1);
        a2 = fmaf(w4.x, bf2f(u0.z), a2);
        a3 = fmaf(w4.x, bf2f(u0.w), a3);
        a0 = fmaf(w4.y, bf2f(u1.x), a0);
        a1 = fmaf(w4.y, bf2f(u1.y), a1);
        a2 = fmaf(w4.y, bf2f(u1.z), a2);
        a3 = fmaf(w4.y, bf2f(u1.w), a3);
        a0 = fmaf(w4.z, bf2f(u2.x), a0);
        a1 = fmaf(w4.z, bf2f(u2.y), a1);
        a2 = fmaf(w4.z, bf2f(u2.z), a2);
        a3 = fmaf(w4.z, bf2f(u2.w), a3);
        a0 = fmaf(w4.w, bf2f(u3.x), a0);
        a1 = fmaf(w4.w, bf2f(u3.y), a1);
        a2 = fmaf(w4.w, bf2f(u3.z), a2);
        a3 = fmaf(w4.w, bf2f(u3.w), a3);
    }

    const int rq = b * LQ + chunk * 32 + qq;
    float4 o; o.x = a0; o.y = a1; o.z = a2; o.w = a3;
    *(float4*)(out_head + (size_t)rq * 256 + (h << 5) + (ln << 2)) = o;
}

// ---------------------------------------------------------------------------
extern "C" void kernel_launch(void* const* d_in, const int* in_sizes, int n_in,
                              void* d_out, int out_size, void* d_ws, size_t ws_size,
                              hipStream_t stream)
{
    const float* query = (const float*)d_in[0];
    const float* refp  = (const float*)d_in[1];
    const float* value = (const float*)d_in[2];
    const float* so_w  = (const float*)d_in[4];
    const float* so_b  = (const float*)d_in[5];
    const float* aw_w  = (const float*)d_in[6];
    const float* aw_b  = (const float*)d_in[7];
    const float* vp_w  = (const float*)d_in[8];
    const float* vp_b  = (const float*)d_in[9];
    const float* op_w  = (const float*)d_in[10];
    const float* op_b  = (const float*)d_in[11];
    float* out = (float*)d_out;

    float* ws = (float*)d_ws;
    size_t off = 0;
    unsigned short* v = (unsigned short*)(ws + off);
    off += (size_t)BSZ * NH * LV * HD / 2;                          // bf16
    unsigned short* wT = (unsigned short*)(ws + off); off += 32768;
    float* so_raw   = ws + off; off += (size_t)BSZ * LQ * 256;
    float* aw_raw   = ws + off; off += (size_t)BSZ * LQ * 128;
    float* out_head = ws + off; off += (size_t)BSZ * LQ * 256;

    // 0) transpose+convert vp_w
    wconv_kernel<<<256, 256, 0, stream>>>(vp_w, wT);

    // 1) value projection (MFMA bf16, register-resident W) -> v
    {
        dim3 grid((VM + 63) / 64);
        vproj_mfma_kernel<<<grid, 256, 0, stream>>>(value, wT, vp_b, v);
    }
    // 2) fused so+aw projection -> so_raw, aw_raw
    {
        dim3 grid(6, BSZ * LQ / 64);
        qproj_kernel<<<grid, 256, 0, stream>>>(query, so_w, so_b, aw_w, aw_b,
                                               so_raw, aw_raw);
    }
    // 3) deformable sampling (inline softmax) -> out_head
    {
        dim3 grid(BSZ * NH * (LQ / 32));
        sample_kernel<<<grid, 256, 0, stream>>>(v, so_raw, aw_raw, refp, out_head);
    }
    // 4) output projection -> d_out
    {
        dim3 grid(256 / 64, BSZ * LQ / 64);
        sgemm_kernel<<<grid, 256, 0, stream>>>(out_head, op_w, op_b, out);
    }
}